// Round 1
// baseline (35044.684 us; speedup 1.0000x reference)
//
#include <hip/hip_runtime.h>
#include <hip/hip_bf16.h>

// Problem dims
#define Bdim 256
#define Sdim 512
#define Cdim 512
#define Hdim 512

typedef __attribute__((ext_vector_type(8))) short bfrag;     // 8 bf16 (4 VGPRs) MFMA A/B frag
typedef __attribute__((ext_vector_type(8))) unsigned short u16x8;
typedef __attribute__((ext_vector_type(4))) float f32x4;     // MFMA C/D frag

__device__ __forceinline__ unsigned short f2bf_rne(float f) {
    union { float f; unsigned u; } v; v.f = f;
    return (unsigned short)((v.u + 0x7fffu + ((v.u >> 16) & 1u)) >> 16);
}
__device__ __forceinline__ float sigmoidf_(float x) { return 1.0f / (1.0f + __expf(-x)); }

// ---------------------------------------------------------------------------
// Pack a K x N fp32 weight into bf16 MFMA B-fragment layout:
//   dst[ (n16*(K/32) + kc)*512 + lane*8 + j ]  holds  B[kc*32 + (lane>>4)*8 + j][n16*16 + (lane&15)]
// TRANS=false: src is (K,N) row-major, B[k][n] = src[k*N+n]   (Q, R)
// TRANS=true : src is (N,K) row-major, B[k][n] = src[n*K+k]   (W*^T uses)
// K is always 512 here (K/32 = 16).
template<bool TRANS>
__global__ __launch_bounds__(256) void pack_weight(const float* __restrict__ src,
                                                   unsigned short* __restrict__ dst,
                                                   int K, int N) {
    int tid = blockIdx.x * 256 + threadIdx.x;
    int total = (K >> 5) * (N >> 4) * 64;
    if (tid >= total) return;
    int lane = tid & 63;
    int blk  = tid >> 6;
    int kc   = blk & 15;        // K/32 == 16
    int n16  = blk >> 4;
    int n  = (n16 << 4) + (lane & 15);
    int kb = (kc << 5) + ((lane >> 4) << 3);
    u16x8 v;
#pragma unroll
    for (int j = 0; j < 8; ++j) {
        int k = kb + j;
        float f = TRANS ? src[(size_t)n * K + k] : src[(size_t)k * N + n];
        v[j] = f2bf_rne(f);
    }
    *(u16x8*)(dst + ((size_t)tid << 3)) = v;
}

__global__ __launch_bounds__(256) void zero_state(float* hf, float* cs, unsigned short* hb) {
    int tid = blockIdx.x * 256 + threadIdx.x;
    if (tid < Bdim * Hdim) { hf[tid] = 0.f; cs[tid] = 0.f; hb[tid] = 0; }
}

// ---------------------------------------------------------------------------
// Mogrifier stage: dst[b][n] = 2*sigmoid( (A @ W)[b][n] ) * prev[b][n]
// A: bf16 row-major (256 x 512). Wp: packed. prev: fp32 with row stride prevStride.
// Writes fp32 master + bf16 copy (row-major, stride 512).
// grid (16, 8) = (N/32, M/32), block 64 (one wave; 2x2 MFMA 16x16x32 subtiles).
__global__ __launch_bounds__(64)
void mog_kernel(const unsigned short* __restrict__ A,
                const unsigned short* __restrict__ Wp,
                const float* __restrict__ prev, long prevStride,
                float* __restrict__ dstf, unsigned short* __restrict__ dstb)
{
    int nt = blockIdx.x, mt = blockIdx.y;
    int lane = threadIdx.x, lm = lane & 15, lq = lane >> 4;
    f32x4 acc[2][2] = {};
    const bfrag* A0 = (const bfrag*)(A + (size_t)(mt*32 +      lm) * 512) + lq;
    const bfrag* A1 = (const bfrag*)(A + (size_t)(mt*32 + 16 + lm) * 512) + lq;
    const bfrag* B0 = (const bfrag*)(Wp + (size_t)(nt*2    ) * 16 * 512) + lane;
    const bfrag* B1 = (const bfrag*)(Wp + (size_t)(nt*2 + 1) * 16 * 512) + lane;
#pragma unroll 4
    for (int kc = 0; kc < 16; ++kc) {
        bfrag a0 = A0[kc*4], a1 = A1[kc*4];
        bfrag b0 = B0[kc*64], b1 = B1[kc*64];
        acc[0][0] = __builtin_amdgcn_mfma_f32_16x16x32_bf16(a0, b0, acc[0][0], 0, 0, 0);
        acc[0][1] = __builtin_amdgcn_mfma_f32_16x16x32_bf16(a0, b1, acc[0][1], 0, 0, 0);
        acc[1][0] = __builtin_amdgcn_mfma_f32_16x16x32_bf16(a1, b0, acc[1][0], 0, 0, 0);
        acc[1][1] = __builtin_amdgcn_mfma_f32_16x16x32_bf16(a1, b1, acc[1][1], 0, 0, 0);
    }
    int nb = nt*32, mb = mt*32;
#pragma unroll
    for (int mi = 0; mi < 2; ++mi)
#pragma unroll
    for (int ni = 0; ni < 2; ++ni) {
        int n = nb + ni*16 + lm;
#pragma unroll
        for (int r = 0; r < 4; ++r) {
            int m = mb + mi*16 + lq*4 + r;   // C/D: col=lane&15, row=(lane>>4)*4+r  [m89]
            float g = 2.0f * sigmoidf_(acc[mi][ni][r]);
            float v = g * prev[(size_t)m * prevStride + n];
            dstf[(size_t)m * 512 + n] = v;
            dstb[(size_t)m * 512 + n] = f2bf_rne(v);
        }
    }
}

// ---------------------------------------------------------------------------
// mt = X @ WmxT + H @ WmhT + bmx + bmh   (bf16 output only; mt is matmul input only)
__global__ __launch_bounds__(64)
void mt_kernel(const unsigned short* __restrict__ X,
               const unsigned short* __restrict__ Hm,
               const unsigned short* __restrict__ W1p,
               const unsigned short* __restrict__ W2p,
               const float* __restrict__ b1, const float* __restrict__ b2,
               unsigned short* __restrict__ mtb)
{
    int nt = blockIdx.x, mt = blockIdx.y;
    int lane = threadIdx.x, lm = lane & 15, lq = lane >> 4;
    f32x4 acc[2][2] = {};
    const unsigned short* As[2] = {X, Hm};
    const unsigned short* Ws[2] = {W1p, W2p};
#pragma unroll
    for (int ph = 0; ph < 2; ++ph) {
        const bfrag* A0 = (const bfrag*)(As[ph] + (size_t)(mt*32 +      lm) * 512) + lq;
        const bfrag* A1 = (const bfrag*)(As[ph] + (size_t)(mt*32 + 16 + lm) * 512) + lq;
        const bfrag* B0 = (const bfrag*)(Ws[ph] + (size_t)(nt*2    ) * 16 * 512) + lane;
        const bfrag* B1 = (const bfrag*)(Ws[ph] + (size_t)(nt*2 + 1) * 16 * 512) + lane;
#pragma unroll 4
        for (int kc = 0; kc < 16; ++kc) {
            bfrag a0 = A0[kc*4], a1 = A1[kc*4];
            bfrag b0 = B0[kc*64], b1 = B1[kc*64];
            acc[0][0] = __builtin_amdgcn_mfma_f32_16x16x32_bf16(a0, b0, acc[0][0], 0, 0, 0);
            acc[0][1] = __builtin_amdgcn_mfma_f32_16x16x32_bf16(a0, b1, acc[0][1], 0, 0, 0);
            acc[1][0] = __builtin_amdgcn_mfma_f32_16x16x32_bf16(a1, b0, acc[1][0], 0, 0, 0);
            acc[1][1] = __builtin_amdgcn_mfma_f32_16x16x32_bf16(a1, b1, acc[1][1], 0, 0, 0);
        }
    }
    int nb = nt*32, mb = mt*32;
#pragma unroll
    for (int mi = 0; mi < 2; ++mi)
#pragma unroll
    for (int ni = 0; ni < 2; ++ni) {
        int n = nb + ni*16 + lm;
        float bias = b1[n] + b2[n];
#pragma unroll
        for (int r = 0; r < 4; ++r) {
            int m = mb + mi*16 + lq*4 + r;
            mtb[(size_t)m * 512 + n] = f2bf_rne(acc[mi][ni][r] + bias);
        }
    }
}

// ---------------------------------------------------------------------------
// gates = X @ WihT + Mt @ WhmT + bih + bhm  (B x 4H), fused LSTM cell update.
// Each WG computes its 32x32 h-tile for ALL 4 gate column-blocks, then the cell.
__global__ __launch_bounds__(64)
void gates_cell_kernel(const unsigned short* __restrict__ X,
                       const unsigned short* __restrict__ Mt,
                       const unsigned short* __restrict__ Wihp,  // K=512, N=2048 packed
                       const unsigned short* __restrict__ Whmp,
                       const float* __restrict__ bih, const float* __restrict__ bhm,
                       float* __restrict__ Cs, float* __restrict__ hf,
                       unsigned short* __restrict__ hb,
                       float* __restrict__ outp /* d_out + t*H, row stride S*H */)
{
    int nt = blockIdx.x, mt = blockIdx.y;
    int lane = threadIdx.x, lm = lane & 15, lq = lane >> 4;
    f32x4 acc[4][2][2] = {};
    const unsigned short* As[2] = {X, Mt};
    const unsigned short* Ws[2] = {Wihp, Whmp};
#pragma unroll
    for (int ph = 0; ph < 2; ++ph) {
        const bfrag* A0 = (const bfrag*)(As[ph] + (size_t)(mt*32 +      lm) * 512) + lq;
        const bfrag* A1 = (const bfrag*)(As[ph] + (size_t)(mt*32 + 16 + lm) * 512) + lq;
        const unsigned short* W = Ws[ph];
#pragma unroll 2
        for (int kc = 0; kc < 16; ++kc) {
            bfrag a0 = A0[kc*4], a1 = A1[kc*4];
#pragma unroll
            for (int g = 0; g < 4; ++g) {
                // n16 block for (gate g, ni): g*32 + nt*2 + ni ; block idx = n16*16 + kc
                const bfrag* B0 = (const bfrag*)(W + ((size_t)(g*32 + nt*2) * 16 + kc) * 512) + lane;
                bfrag b0 = B0[0];
                bfrag b1 = B0[1024];   // next n16 block: +16 blocks * 512 elems = +1024 bfrags
                acc[g][0][0] = __builtin_amdgcn_mfma_f32_16x16x32_bf16(a0, b0, acc[g][0][0], 0, 0, 0);
                acc[g][0][1] = __builtin_amdgcn_mfma_f32_16x16x32_bf16(a0, b1, acc[g][0][1], 0, 0, 0);
                acc[g][1][0] = __builtin_amdgcn_mfma_f32_16x16x32_bf16(a1, b0, acc[g][1][0], 0, 0, 0);
                acc[g][1][1] = __builtin_amdgcn_mfma_f32_16x16x32_bf16(a1, b1, acc[g][1][1], 0, 0, 0);
            }
        }
    }
    int nb = nt*32, mb = mt*32;
#pragma unroll
    for (int mi = 0; mi < 2; ++mi)
#pragma unroll
    for (int ni = 0; ni < 2; ++ni) {
        int n = nb + ni*16 + lm;
        float bi = bih[n]        + bhm[n];
        float bf = bih[512 + n]  + bhm[512 + n];
        float bg = bih[1024 + n] + bhm[1024 + n];
        float bo = bih[1536 + n] + bhm[1536 + n];
#pragma unroll
        for (int r = 0; r < 4; ++r) {
            int m = mb + mi*16 + lq*4 + r;
            size_t idx = (size_t)m * 512 + n;
            float ig = sigmoidf_(acc[0][mi][ni][r] + bi);
            float fg = sigmoidf_(acc[1][mi][ni][r] + bf);
            float gg = tanhf    (acc[2][mi][ni][r] + bg);
            float og = sigmoidf_(acc[3][mi][ni][r] + bo);
            float c  = fg * Cs[idx] + ig * gg;
            Cs[idx] = c;
            float h = og * tanhf(c);
            hf[idx] = h;
            hb[idx] = f2bf_rne(h);
            outp[(size_t)m * (Sdim * Hdim) + n] = h;
        }
    }
}

// ---------------------------------------------------------------------------
extern "C" void kernel_launch(void* const* d_in, const int* in_sizes, int n_in,
                              void* d_out, int out_size, void* d_ws, size_t ws_size,
                              hipStream_t stream) {
    const float* x     = (const float*)d_in[0];
    const float* Wih_w = (const float*)d_in[1];
    const float* Wih_b = (const float*)d_in[2];
    const float* Wmx_w = (const float*)d_in[3];
    const float* Wmx_b = (const float*)d_in[4];
    const float* Wmh_w = (const float*)d_in[5];
    const float* Wmh_b = (const float*)d_in[6];
    const float* Whm_w = (const float*)d_in[7];
    const float* Whm_b = (const float*)d_in[8];
    const float* Q     = (const float*)d_in[9];
    const float* R     = (const float*)d_in[10];
    float* out = (float*)d_out;

    // workspace layout (~8.25 MB)
    unsigned short* packQ   = (unsigned short*)d_ws;
    unsigned short* packR   = packQ   + 512 * 512;
    unsigned short* packWmx = packR   + 512 * 512;   // Wmx^T packed
    unsigned short* packWmh = packWmx + 512 * 512;   // Wmh^T packed
    unsigned short* packWih = packWmh + 512 * 512;   // Wih^T packed (512 x 2048)
    unsigned short* packWhm = packWih + 512 * 2048;  // Whm^T packed (512 x 2048)
    float* xtf = (float*)(packWhm + 512 * 2048);
    float* hf  = xtf + Bdim * Cdim;
    float* cs  = hf  + Bdim * Hdim;
    unsigned short* xtb = (unsigned short*)(cs + Bdim * Hdim);
    unsigned short* hb  = xtb + Bdim * Cdim;
    unsigned short* mtb = hb  + Bdim * Hdim;

    // Pack weights (once per launch; ws is re-poisoned before every call)
    pack_weight<false><<<dim3(128), dim3(256), 0, stream>>>(Q,     packQ,   512, 512);
    pack_weight<false><<<dim3(128), dim3(256), 0, stream>>>(R,     packR,   512, 512);
    pack_weight<true ><<<dim3(128), dim3(256), 0, stream>>>(Wmx_w, packWmx, 512, 512);
    pack_weight<true ><<<dim3(128), dim3(256), 0, stream>>>(Wmh_w, packWmh, 512, 512);
    pack_weight<true ><<<dim3(512), dim3(256), 0, stream>>>(Wih_w, packWih, 512, 2048);
    pack_weight<true ><<<dim3(512), dim3(256), 0, stream>>>(Whm_w, packWhm, 512, 2048);
    zero_state<<<dim3(512), dim3(256), 0, stream>>>(hf, cs, hb);

    dim3 grid(16, 8), block(64);
    for (int t = 0; t < Sdim; ++t) {
        const float* xsrc = x + (size_t)t * Cdim;  // row stride S*C
        // mogrifier i=1..5 (odd: update x via Q; even: update h via R)
        mog_kernel<<<grid, block, 0, stream>>>(hb,  packQ, xsrc, (long)(Sdim * Cdim), xtf, xtb);
        mog_kernel<<<grid, block, 0, stream>>>(xtb, packR, hf,   512, hf,  hb);
        mog_kernel<<<grid, block, 0, stream>>>(hb,  packQ, xtf,  512, xtf, xtb);
        mog_kernel<<<grid, block, 0, stream>>>(xtb, packR, hf,   512, hf,  hb);
        mog_kernel<<<grid, block, 0, stream>>>(hb,  packQ, xtf,  512, xtf, xtb);
        // mt and gates + fused cell
        mt_kernel<<<grid, block, 0, stream>>>(xtb, hb, packWmx, packWmh, Wmx_b, Wmh_b, mtb);
        gates_cell_kernel<<<grid, block, 0, stream>>>(xtb, mtb, packWih, packWhm,
                                                      Wih_b, Whm_b, cs, hf, hb,
                                                      out + (size_t)t * Hdim);
    }
}